// Round 15
// baseline (7740.691 us; speedup 1.0000x reference)
//
#include <hip/hip_runtime.h>

typedef _Float16 h2 __attribute__((ext_vector_type(2)));

__device__ __forceinline__ h2 mkh2(float a, float b) {
    h2 r; r.x = (_Float16)a; r.y = (_Float16)b; return r;
}
__device__ __forceinline__ h2 bc(unsigned u) {
    union { unsigned u; h2 h; } c; c.u = u; return c.h;
}

// DPP quad-perm lane exchange (VALU, no LDS): 0xB1 = swap lane^1
template <int CTRL>
__device__ __forceinline__ float dpp_q(float v) {
    int i = __builtin_bit_cast(int, v);
    int r = __builtin_amdgcn_update_dpp(0, i, CTRL, 0xF, 0xF, true);
    return __builtin_bit_cast(float, r);
}

// 4 fdot2 of one uint4 chunk into the row-A accumulators.
#define DOT4A(Q, i) do {                                              \
    aA0 = __builtin_amdgcn_fdot2(WA[4*i+0], bc(Q.x), aA0, false);     \
    aA1 = __builtin_amdgcn_fdot2(WA[4*i+1], bc(Q.y), aA1, false);     \
    aA2 = __builtin_amdgcn_fdot2(WA[4*i+2], bc(Q.z), aA2, false);     \
    aA3 = __builtin_amdgcn_fdot2(WA[4*i+3], bc(Q.w), aA3, false);     \
} while (0)
// 4 fdot2 of one uint4 chunk into the row-B accumulators.
#define DOT4B(Q, i) do {                                              \
    aB0 = __builtin_amdgcn_fdot2(WB[4*i+0], bc(Q.x), aB0, false);     \
    aB1 = __builtin_amdgcn_fdot2(WB[4*i+1], bc(Q.y), aB1, false);     \
    aB2 = __builtin_amdgcn_fdot2(WB[4*i+2], bc(Q.z), aB2, false);     \
    aB3 = __builtin_amdgcn_fdot2(WB[4*i+3], bc(Q.w), aB3, false);     \
} while (0)

#define SBAR() __builtin_amdgcn_sched_barrier(0)

// Gate-wave barrier: drain to 5 outstanding LDS ops — guarantees the hbuf
// write (oldest) retired; the 4 own-chunk pre-reads AND the hist write stay
// in flight across the barrier (hist isn't read for >=63 steps).
#define BARRIER5() asm volatile("s_waitcnt lgkmcnt(5)\n\ts_barrier" ::: "memory")
// Head-wave barrier: full LDS drain.
#define BARRIER0() asm volatile("s_waitcnt lgkmcnt(0)\n\ts_barrier" ::: "memory")

// 96-wide f32 dot of one LDS history row against w_dense.
__device__ __forceinline__ float head_dot(const float* hrow, const float* wdp) {
    const float4* hr = reinterpret_cast<const float4*>(hrow);
    const float4* wv = reinterpret_cast<const float4*>(wdp);
    float a0 = 0.f, a1 = 0.f, a2 = 0.f, a3 = 0.f;
    #pragma unroll
    for (int k = 0; k < 24; k += 4) {
        float4 ha = hr[k], hb = hr[k + 1], hc = hr[k + 2], hd = hr[k + 3];
        float4 wa = wv[k], wb = wv[k + 1], wc = wv[k + 2], wd = wv[k + 3];
        a0 = fmaf(ha.w, wa.w, fmaf(ha.z, wa.z, fmaf(ha.y, wa.y, fmaf(ha.x, wa.x, a0))));
        a1 = fmaf(hb.w, wb.w, fmaf(hb.z, wb.z, fmaf(hb.y, wb.y, fmaf(hb.x, wb.x, a1))));
        a2 = fmaf(hc.w, wc.w, fmaf(hc.z, wc.z, fmaf(hc.y, wc.y, fmaf(hc.x, wc.x, a2))));
        a3 = fmaf(hd.w, wd.w, fmaf(hd.z, wd.z, fmaf(hd.y, wd.y, fmaf(hd.x, wd.x, a3))));
    }
    return (a0 + a1) + (a2 + a3);
}

// 4 waves (1 per SIMD): 0..2 gate waves (each lane owns TWO w_hh rows), 3 head.
// Lane (u, p): u = 32*wv + (lane>>1), p = lane&1.
//   p==0: rows u (i, sigmoid) and 192+u (g, tanh); p==1: 96+u (f), 288+u (o).
// Weights PRE-SCALED by -log2e / -2log2e (activation = rcp(1+exp2(pre))).
// Cell state kept PRE-SCALED: cs = -2log2e * c, so tanh(c) = 2*rcp(1+exp2(cs))-1
// with no multiply on the c->h chain.
// Weights loaded ROTATED so dot slots 0..3 are the wave's OWN h-chunk
// (pre-read before the barrier, in flight across it).
// Schedule: own A+B interleaved (64cy read cover) -> A non-own -> exp2A ->
// B non-own 1st half -> rcpA/swap/i' -> B 2nd half -> short tail.
__global__ __launch_bounds__(256, 1)
void lstm_fused(
    const float* __restrict__ x,        // [B,T]
    const float* __restrict__ w_ih,     // [384]
    const float* __restrict__ w_hh,     // [384,96]
    const float* __restrict__ b_ih,     // [384]
    const float* __restrict__ b_hh,     // [384]
    const float* __restrict__ w_dense,  // [96]
    const float* __restrict__ b_dense,  // [1]
    float* __restrict__ out,            // [B,T]
    int T)
{
    const int tid  = threadIdx.x;    // 0..255
    const int lane = tid & 63;
    const int wv   = tid >> 6;       // 0..2 gate, 3 head

    __shared__ __align__(16) _Float16 hbuf[2][96];    // double-buffered h (f16)
    __shared__ __align__(16) float hist[2][64][100];  // h history for the head

    if (tid < 96) { hbuf[0][tid] = (_Float16)0.f; hbuf[1][tid] = (_Float16)0.f; }

    const float* xrow = x + (size_t)blockIdx.x * T;
    float*       orow = out + (size_t)blockIdx.x * T;

    __syncthreads();

    if (wv < 3) {
        const int p = lane & 1;
        const int u = (wv << 5) | (lane >> 1);   // hidden unit 0..95
        const int rowA = 96 * p + u;             // p0: i-row, p1: f-row
        const int rowB = 96 * (2 + p) + u;       // p0: g-row, p1: o-row

        // Activation exp2-scales: row A always sigmoid; row B tanh iff p==0.
        const float nkA = -1.442695041f;
        const float nkB = (p == 0) ? -2.885390082f : -1.442695041f;
        const float m1B = (p == 0) ? 2.f : 1.f;
        const float d1B = (p == 0) ? -1.f : 0.f;

        // Rotated + pre-scaled weight load: dot-slot j consumes h chunk
        // (4*wv+j)%12, so slots 0..3 are the wave's OWN chunk.
        h2 WA[48], WB[48];
        {
            const float4* ra = reinterpret_cast<const float4*>(w_hh + (size_t)rowA * 96);
            const float4* rb = reinterpret_cast<const float4*>(w_hh + (size_t)rowB * 96);
            #pragma unroll
            for (int j = 0; j < 12; ++j) {
                int cc = 4 * wv + j; if (cc >= 12) cc -= 12;
                float4 fa = ra[2 * cc], ga = ra[2 * cc + 1];
                WA[4*j+0] = mkh2(nkA * fa.x, nkA * fa.y);
                WA[4*j+1] = mkh2(nkA * fa.z, nkA * fa.w);
                WA[4*j+2] = mkh2(nkA * ga.x, nkA * ga.y);
                WA[4*j+3] = mkh2(nkA * ga.z, nkA * ga.w);
                float4 fb = rb[2 * cc], gb = rb[2 * cc + 1];
                WB[4*j+0] = mkh2(nkB * fb.x, nkB * fb.y);
                WB[4*j+1] = mkh2(nkB * fb.z, nkB * fb.w);
                WB[4*j+2] = mkh2(nkB * gb.x, nkB * gb.y);
                WB[4*j+3] = mkh2(nkB * gb.z, nkB * gb.w);
            }
        }

        // Scaled x/bias constants (xb computed fully in the shadow).
        const float wihAs  = nkA * w_ih[rowA];
        const float wihBs  = nkB * w_ih[rowB];
        const float biasAs = nkA * (b_ih[rowA] + b_hh[rowA]);
        const float biasBs = nkB * (b_ih[rowB] + b_hh[rowB]);

        // Remaining chunk indices (runtime constants per wave).
        int c4  = 4*wv + 4;  if (c4  >= 12) c4  -= 12;
        int c5  = 4*wv + 5;  if (c5  >= 12) c5  -= 12;
        int c6  = 4*wv + 6;  if (c6  >= 12) c6  -= 12;
        int c7  = 4*wv + 7;  if (c7  >= 12) c7  -= 12;
        int c8  = 4*wv + 8;  if (c8  >= 12) c8  -= 12;
        int c9  = 4*wv + 9;  if (c9  >= 12) c9  -= 12;
        int c10 = 4*wv + 10; if (c10 >= 12) c10 -= 12;
        int c11 = 4*wv + 11; if (c11 >= 12) c11 -= 12;

        float cs  = 0.f;                              // = -2log2e * c
        float xbA = fmaf(xrow[0], wihAs, biasAs);
        float xbB = fmaf(xrow[0], wihBs, biasBs);

        // Prologue: own-chunk pre-read of the t=0 source buffer (hbuf[1], zeros).
        const uint4* hp0 = reinterpret_cast<const uint4*>(hbuf[1]);
        uint4 qO0 = hp0[4*wv + 0], qO1 = hp0[4*wv + 1];
        uint4 qO2 = hp0[4*wv + 2], qO3 = hp0[4*wv + 3];

        #pragma unroll 1
        for (int t = 0; t < T; ++t) {
            int tn = (t + 1 < T) ? t + 1 : T - 1;
            float xs_n  = xrow[tn];                       // global prefetch
            float xbA_n = fmaf(xs_n, wihAs, biasAs);      // shadow fmafs
            float xbB_n = fmaf(xs_n, wihBs, biasBs);

            const uint4* hp = reinterpret_cast<const uint4*>(hbuf[(t & 1) ^ 1]);
            // Issue the 8 non-own reads; all 12 chunks stay live for pass B.
            uint4 q4 = hp[c4],  q5 = hp[c5],  q6 = hp[c6],  q7 = hp[c7];
            uint4 q8 = hp[c8],  q9 = hp[c9],  qa = hp[c10], qb = hp[c11];

            // ---- phase 1: own chunks, A+B interleaved (64 cy read cover) ----
            float aA0 = xbA, aA1 = 0.f, aA2 = 0.f, aA3 = 0.f;
            float aB0 = xbB, aB1 = 0.f, aB2 = 0.f, aB3 = 0.f;
            DOT4A(qO0, 0); DOT4B(qO0, 0); DOT4A(qO1, 1); DOT4B(qO1, 1);
            DOT4A(qO2, 2); DOT4B(qO2, 2); DOT4A(qO3, 3); DOT4B(qO3, 3);
            SBAR();
            // ---- phase 2: A non-own (reads have had >=64 cy) ----
            DOT4A(q4, 4);  DOT4A(q5, 5);  DOT4A(q6, 6);  DOT4A(q7, 7);
            DOT4A(q8, 8);  DOT4A(q9, 9);  DOT4A(qa, 10); DOT4A(qb, 11);
            SBAR();
            // ---- phase 3: A-activation head (latency hides under phase 4) ----
            float preA = (aA0 + aA1) + (aA2 + aA3);
            float eA   = __builtin_exp2f(preA);
            SBAR();
            // ---- phase 4: B non-own, first half ----
            DOT4B(q4, 4);  DOT4B(q5, 5);  DOT4B(q6, 6);  DOT4B(q7, 7);
            SBAR();
            float actA = __builtin_amdgcn_rcpf(1.f + eA);   // i (p0) / f (p1)
            float oA   = dpp_q<0xB1>(actA);                 // f (p0) / i (p1)
            float iS   = actA * -2.885390082f;              // pre-scaled i (p0)
            SBAR();
            // ---- phase 5: B non-own, second half ----
            DOT4B(q8, 8);  DOT4B(q9, 9);  DOT4B(qa, 10); DOT4B(qb, 11);
            SBAR();
            // ---- short tail ----
            float preB = (aB0 + aB1) + (aB2 + aB3);
            float actB = fmaf(m1B, __builtin_amdgcn_rcpf(1.f + __builtin_exp2f(preB)), d1B);
            float oB   = dpp_q<0xB1>(actB);                 // o (p0) / g (p1)

            float hval = 0.f;
            if (p == 0) {   // owns unit u: actA=i, actB=g, oA=f, oB=o
                cs = fmaf(oA, cs, iS * actB);               // cs = -2log2e * c
                float th = fmaf(2.f, __builtin_amdgcn_rcpf(1.f + __builtin_exp2f(cs)), -1.f);
                hval = oB * th;
                hbuf[t & 1][u] = (_Float16)hval;            // matvec path (critical)
            }

            // Pin order: hbuf write above; own-chunk pre-reads of the
            // just-written buffer; hist write (off-critical, crosses barrier).
            SBAR();
            const uint4* hw = reinterpret_cast<const uint4*>(hbuf[t & 1]);
            qO0 = hw[4*wv + 0]; qO1 = hw[4*wv + 1];
            qO2 = hw[4*wv + 2]; qO3 = hw[4*wv + 3];
            if (p == 0) hist[(t >> 6) & 1][t & 63][u] = hval;
            SBAR();

            BARRIER5();   // hbuf write drained; pre-reads + hist write in flight
            xbA = xbA_n; xbB = xbB_n;
        }
    } else {
        // ---- head wave: one burst of 64 outputs per 64-step window ----
        const float bd = b_dense[0];
        #pragma unroll 1
        for (int t = 0; t < T; ++t) {
            if (t && (t & 63) == 0) {
                const int buf = ((t >> 6) - 1) & 1;    // completed window
                float a = head_dot(&hist[buf][lane][0], w_dense);
                orow[t - 64 + lane] = a + bd;
            }
            BARRIER0();
        }
        // tail: rows [T0, T)
        const int T0 = ((T - 1) >> 6) << 6;
        if (lane < T - T0) {
            const int buf = (T0 >> 6) & 1;
            float a = head_dot(&hist[buf][lane][0], w_dense);
            orow[T0 + lane] = a + bd;
        }
    }
}

extern "C" void kernel_launch(void* const* d_in, const int* in_sizes, int n_in,
                              void* d_out, int out_size, void* d_ws, size_t ws_size,
                              hipStream_t stream) {
    const float* x   = (const float*)d_in[0];
    const float* wih = (const float*)d_in[1];
    const float* whh = (const float*)d_in[2];
    const float* bih = (const float*)d_in[3];
    const float* bhh = (const float*)d_in[4];
    const float* wd  = (const float*)d_in[5];
    const float* bd  = (const float*)d_in[6];
    float* out = (float*)d_out;

    const int B = 32;
    const int T = in_sizes[0] / B;   // x is [B,T,1]

    lstm_fused<<<dim3(B), dim3(256), 0, stream>>>(x, wih, whh, bih, bhh, wd, bd, out, T);
}